// Round 3
// baseline (68.183 us; speedup 1.0000x reference)
//
#include <hip/hip_runtime.h>
#include <math.h>

#define PB  64    // blocks per batch
#define TPB 256
#define B_  32    // batch count (fixed by setup_inputs)

// ws layout:
//   float partials[B*PB]   deterministic per-(batch,block) slots
//   unsigned counter       zeroed by a memset node each call

__global__ __launch_bounds__(TPB) void fused_kernel(
    const float* __restrict__ predT,
    const float4* __restrict__ pts,
    const float* __restrict__ target,
    const float* __restrict__ R_rect,
    const float* __restrict__ RT,
    const int* __restrict__ sizes,
    float* __restrict__ partials,
    unsigned* __restrict__ counter,
    float* __restrict__ out,
    int N)
{
    const int b   = blockIdx.y;
    const int blk = blockIdx.x;
    const int tid = threadIdx.x;

    // ---- per-thread redundant prep: branch-free, static-index only (no scratch)
    // C = R_rect @ RT
    float c[16];
    #pragma unroll
    for (int i = 0; i < 4; ++i)
        #pragma unroll
        for (int j = 0; j < 4; ++j)
            c[i*4+j] = R_rect[i*4+0]*RT[0*4+j] + R_rect[i*4+1]*RT[1*4+j]
                     + R_rect[i*4+2]*RT[2*4+j] + R_rect[i*4+3]*RT[3*4+j];

    // MESA-style adjugate inverse (row-major). inv = adj/det.
    float i00 =  c[5]*c[10]*c[15] - c[5]*c[11]*c[14] - c[9]*c[6]*c[15]
               + c[9]*c[7]*c[14] + c[13]*c[6]*c[11] - c[13]*c[7]*c[10];
    float i04 = -c[4]*c[10]*c[15] + c[4]*c[11]*c[14] + c[8]*c[6]*c[15]
               - c[8]*c[7]*c[14] - c[12]*c[6]*c[11] + c[12]*c[7]*c[10];
    float i08 =  c[4]*c[9]*c[15] - c[4]*c[11]*c[13] - c[8]*c[5]*c[15]
               + c[8]*c[7]*c[13] + c[12]*c[5]*c[11] - c[12]*c[7]*c[9];
    float i12 = -c[4]*c[9]*c[14] + c[4]*c[10]*c[13] + c[8]*c[5]*c[14]
               - c[8]*c[6]*c[13] - c[12]*c[5]*c[10] + c[12]*c[6]*c[9];
    float i01 = -c[1]*c[10]*c[15] + c[1]*c[11]*c[14] + c[9]*c[2]*c[15]
               - c[9]*c[3]*c[14] - c[13]*c[2]*c[11] + c[13]*c[3]*c[10];
    float i05 =  c[0]*c[10]*c[15] - c[0]*c[11]*c[14] - c[8]*c[2]*c[15]
               + c[8]*c[3]*c[14] + c[12]*c[2]*c[11] - c[12]*c[3]*c[10];
    float i09 = -c[0]*c[9]*c[15] + c[0]*c[11]*c[13] + c[8]*c[1]*c[15]
               - c[8]*c[3]*c[13] - c[12]*c[1]*c[11] + c[12]*c[3]*c[9];
    float i13 =  c[0]*c[9]*c[14] - c[0]*c[10]*c[13] - c[8]*c[1]*c[14]
               + c[8]*c[2]*c[13] + c[12]*c[1]*c[10] - c[12]*c[2]*c[9];
    float i02 =  c[1]*c[6]*c[15] - c[1]*c[7]*c[14] - c[5]*c[2]*c[15]
               + c[5]*c[3]*c[14] + c[13]*c[2]*c[7] - c[13]*c[3]*c[6];
    float i06 = -c[0]*c[6]*c[15] + c[0]*c[7]*c[14] + c[4]*c[2]*c[15]
               - c[4]*c[3]*c[14] - c[12]*c[2]*c[7] + c[12]*c[3]*c[6];
    float i10 =  c[0]*c[5]*c[15] - c[0]*c[7]*c[13] - c[4]*c[1]*c[15]
               + c[4]*c[3]*c[13] + c[12]*c[1]*c[7] - c[12]*c[3]*c[5];
    float i14 = -c[0]*c[5]*c[14] + c[0]*c[6]*c[13] + c[4]*c[1]*c[14]
               - c[4]*c[2]*c[13] - c[12]*c[1]*c[6] + c[12]*c[2]*c[5];
    float i03 = -c[1]*c[6]*c[11] + c[1]*c[7]*c[10] + c[5]*c[2]*c[11]
               - c[5]*c[3]*c[10] - c[9]*c[2]*c[7] + c[9]*c[3]*c[6];
    float i07 =  c[0]*c[6]*c[11] - c[0]*c[7]*c[10] - c[4]*c[2]*c[11]
               + c[4]*c[3]*c[10] + c[8]*c[2]*c[7] - c[8]*c[3]*c[6];
    float i11 = -c[0]*c[5]*c[11] + c[0]*c[7]*c[9] + c[4]*c[1]*c[11]
               - c[4]*c[3]*c[9] - c[8]*c[1]*c[7] + c[8]*c[3]*c[5];
    float i15 =  c[0]*c[5]*c[10] - c[0]*c[6]*c[9] - c[4]*c[1]*c[10]
               + c[4]*c[2]*c[9] + c[8]*c[1]*c[6] - c[8]*c[2]*c[5];
    float det = c[0]*i00 + c[1]*i04 + c[2]*i08 + c[3]*i12;
    float id  = 1.f / det;
    // invC rows 0..2 (row-major): [i00 i01 i02 i03; i04 i05 i06 i07; i08 i09 i10 i11] * id
    float v00=i00*id, v01=i01*id, v02=i02*id, v03=i03*id;
    float v10=i04*id, v11=i05*id, v12=i06*id, v13=i07*id;
    float v20=i08*id, v21=i09*id, v22=i10*id, v23=i11*id;

    // quaternion -> R, D = (target - predSE3)[:3,:], fold: dist = || D3 @ (V3 p + v.3) + D.3 ||
    const float* q = predT + b*7;
    float qr = q[0], qi = q[1], qj = q[2], qk = q[3];
    float tx = q[4], ty = q[5], tz = q[6];
    float s2 = 2.f / (qr*qr + qi*qi + qj*qj + qk*qk);
    float R00 = 1.f - s2*(qj*qj + qk*qk), R01 = s2*(qi*qj - qk*qr), R02 = s2*(qi*qk + qj*qr);
    float R10 = s2*(qi*qj + qk*qr), R11 = 1.f - s2*(qi*qi + qk*qk), R12 = s2*(qj*qk - qi*qr);
    float R20 = s2*(qi*qk - qj*qr), R21 = s2*(qj*qk + qi*qr), R22 = 1.f - s2*(qi*qi + qj*qj);

    const float* T = target + b*16;
    float D00 = T[0]-R00,  D01 = T[1]-R01,  D02 = T[2]-R02,  D03 = T[3]-tx;
    float D10 = T[4]-R10,  D11 = T[5]-R11,  D12 = T[6]-R12,  D13 = T[7]-ty;
    float D20 = T[8]-R20,  D21 = T[9]-R21,  D22 = T[10]-R22, D23 = T[11]-tz;

    float m00 = D00*v00 + D01*v10 + D02*v20;
    float m01 = D00*v01 + D01*v11 + D02*v21;
    float m02 = D00*v02 + D01*v12 + D02*v22;
    float m10 = D10*v00 + D11*v10 + D12*v20;
    float m11 = D10*v01 + D11*v11 + D12*v21;
    float m12 = D10*v02 + D11*v12 + D12*v22;
    float m20 = D20*v00 + D21*v10 + D22*v20;
    float m21 = D20*v01 + D21*v11 + D22*v21;
    float m22 = D20*v02 + D21*v12 + D22*v22;
    float t0  = D00*v03 + D01*v13 + D02*v23 + D03;
    float t1  = D10*v03 + D11*v13 + D12*v23 + D13;
    float t2  = D20*v03 + D21*v13 + D22*v23 + D23;

    // ---- stream the points
    const int size = sizes[b];
    const float4* p = pts + (size_t)b * N;

    float acc = 0.f;
    for (int n = blk * TPB + tid; n < size; n += PB * TPB) {
        float4 v = p[n];
        float dx = m00*v.x + m01*v.y + m02*v.z + t0;
        float dy = m10*v.x + m11*v.y + m12*v.z + t1;
        float dz = m20*v.x + m21*v.y + m22*v.z + t2;
        acc += sqrtf(dx*dx + dy*dy + dz*dz);
    }

    __shared__ float sm[TPB/64];
    __shared__ bool  isLast;
    for (int off = 32; off > 0; off >>= 1) acc += __shfl_down(acc, off);
    if ((tid & 63) == 0) sm[tid >> 6] = acc;
    __syncthreads();
    if (tid == 0) {
        float s = 0.f;
        #pragma unroll
        for (int w = 0; w < TPB/64; ++w) s += sm[w];
        partials[b * PB + blk] = s;           // fixed slot -> deterministic
        __threadfence();                       // release partials
        unsigned old = atomicAdd(counter, 1u);
        isLast = (old == (unsigned)(PB * B_ - 1));
    }
    __syncthreads();
    if (!isLast) return;

    // ---- last block: final reduction + scalar losses
    __threadfence();                           // acquire partials

    __shared__ float sB[B_];
    {
        int bb = tid >> 3, j = tid & 7;        // 8 threads per batch, 8 slots each
        float s = 0.f;
        const float* pp = partials + bb * PB + j * 8;
        #pragma unroll
        for (int i = 0; i < 8; ++i) s += pp[i];
        s += __shfl_down(s, 4);
        s += __shfl_down(s, 2);
        s += __shfl_down(s, 1);
        if (j == 0) {
            int sz = sizes[bb];
            sB[bb] = s / (float)(sz > 1 ? sz : 1);
        }
    }
    __syncthreads();

    if (tid < 64) {
        float accE = 0.f, accT = 0.f, accR = 0.f;
        if (tid < B_) {
            accE = sB[tid];
            const float* qq = predT + tid*7;
            float r = qq[0], ii = qq[1], jj = qq[2], kk = qq[3];
            float px = qq[4], py = qq[5], pz = qq[6];
            float ss = 2.f / (r*r + ii*ii + jj*jj + kk*kk);
            float A00 = 1.f - ss*(jj*jj + kk*kk), A01 = ss*(ii*jj - kk*r), A02 = ss*(ii*kk + jj*r);
            float A10 = ss*(ii*jj + kk*r), A11 = 1.f - ss*(ii*ii + kk*kk), A12 = ss*(jj*kk - ii*r);
            float A20 = ss*(ii*kk - jj*r), A21 = ss*(jj*kk + ii*r), A22 = 1.f - ss*(ii*ii + jj*jj);
            const float* TT = target + tid*16;
            float rl = 0.f;
            // M = A^T @ gtR; ||M - I||_F
            {
                float m;
                m = A00*TT[0] + A10*TT[4] + A20*TT[8]  - 1.f; rl += m*m;
                m = A00*TT[1] + A10*TT[5] + A20*TT[9];        rl += m*m;
                m = A00*TT[2] + A10*TT[6] + A20*TT[10];       rl += m*m;
                m = A01*TT[0] + A11*TT[4] + A21*TT[8];        rl += m*m;
                m = A01*TT[1] + A11*TT[5] + A21*TT[9]  - 1.f; rl += m*m;
                m = A01*TT[2] + A11*TT[6] + A21*TT[10];       rl += m*m;
                m = A02*TT[0] + A12*TT[4] + A22*TT[8];        rl += m*m;
                m = A02*TT[1] + A12*TT[5] + A22*TT[9];        rl += m*m;
                m = A02*TT[2] + A12*TT[6] + A22*TT[10] - 1.f; rl += m*m;
            }
            accR = sqrtf(rl);
            float dx = px - TT[3], dy = py - TT[7], dz = pz - TT[11];
            accT = sqrtf(dx*dx + dy*dy + dz*dz);
        }
        for (int off = 32; off > 0; off >>= 1) {
            accE += __shfl_down(accE, off);
            accT += __shfl_down(accT, off);
            accR += __shfl_down(accR, off);
        }
        if (tid == 0) {
            float eucl = accE / (float)B_;
            out[0] = eucl + 1.5f * (accT / (float)B_) + 2.0f * (accR / (float)B_);
            out[1] = eucl;
        }
    }
}

extern "C" void kernel_launch(void* const* d_in, const int* in_sizes, int n_in,
                              void* d_out, int out_size, void* d_ws, size_t ws_size,
                              hipStream_t stream) {
    const float* predT  = (const float*)d_in[0];
    const float* ptCld  = (const float*)d_in[1];
    const float* target = (const float*)d_in[2];
    const float* R_rect = (const float*)d_in[3];
    const float* RT     = (const float*)d_in[4];
    const int*   sizes  = (const int*)d_in[5];

    int B = in_sizes[0] / 7;            // == B_ (32)
    int N = in_sizes[1] / (B * 4);

    float*    partials = (float*)d_ws;
    unsigned* counter  = (unsigned*)(partials + B * PB);
    float*    out      = (float*)d_out;

    hipMemsetAsync(counter, 0, sizeof(unsigned), stream);
    fused_kernel<<<dim3(PB, B), TPB, 0, stream>>>(
        predT, (const float4*)ptCld, target, R_rect, RT, sizes,
        partials, counter, out, N);
}

// Round 4
// 38.778 us; speedup vs baseline: 1.7583x; 1.7583x over previous
//
#include <hip/hip_runtime.h>
#include <math.h>

#define PB  64    // blocks per batch
#define TPB 256
#define B_  32    // batch count (fixed by setup_inputs)

// ws layout:
//   float partials[B*PB]   deterministic per-(batch,block) slots
//   unsigned counter       zeroed by a memset node each call
//
// Cross-block handshake uses device-scope RELAXED atomics (sc0/sc1 ops that
// go to the point of coherency) ordered by s_waitcnt vmcnt(0) — NOT
// __threadfence(), whose agent-scope fence emits buffer_wbl2 (full L2
// writeback) on gfx950 and cost ~70us across 2048 blocks in rounds 2-3.

__global__ __launch_bounds__(TPB) void fused_kernel(
    const float* __restrict__ predT,
    const float4* __restrict__ pts,
    const float* __restrict__ target,
    const float* __restrict__ R_rect,
    const float* __restrict__ RT,
    const int* __restrict__ sizes,
    float* __restrict__ partials,
    unsigned* __restrict__ counter,
    float* __restrict__ out,
    int N)
{
    const int b   = blockIdx.y;
    const int blk = blockIdx.x;
    const int tid = threadIdx.x;

    // ---- per-thread redundant prep: branch-free, static-index only (registers)
    float c[16];
    #pragma unroll
    for (int i = 0; i < 4; ++i)
        #pragma unroll
        for (int j = 0; j < 4; ++j)
            c[i*4+j] = R_rect[i*4+0]*RT[0*4+j] + R_rect[i*4+1]*RT[1*4+j]
                     + R_rect[i*4+2]*RT[2*4+j] + R_rect[i*4+3]*RT[3*4+j];

    // adjugate inverse rows 0..2 (inv = adj/det), all named scalars
    float i00 =  c[5]*c[10]*c[15] - c[5]*c[11]*c[14] - c[9]*c[6]*c[15]
               + c[9]*c[7]*c[14] + c[13]*c[6]*c[11] - c[13]*c[7]*c[10];
    float i04 = -c[4]*c[10]*c[15] + c[4]*c[11]*c[14] + c[8]*c[6]*c[15]
               - c[8]*c[7]*c[14] - c[12]*c[6]*c[11] + c[12]*c[7]*c[10];
    float i08 =  c[4]*c[9]*c[15] - c[4]*c[11]*c[13] - c[8]*c[5]*c[15]
               + c[8]*c[7]*c[13] + c[12]*c[5]*c[11] - c[12]*c[7]*c[9];
    float i12 = -c[4]*c[9]*c[14] + c[4]*c[10]*c[13] + c[8]*c[5]*c[14]
               - c[8]*c[6]*c[13] - c[12]*c[5]*c[10] + c[12]*c[6]*c[9];
    float i01 = -c[1]*c[10]*c[15] + c[1]*c[11]*c[14] + c[9]*c[2]*c[15]
               - c[9]*c[3]*c[14] - c[13]*c[2]*c[11] + c[13]*c[3]*c[10];
    float i05 =  c[0]*c[10]*c[15] - c[0]*c[11]*c[14] - c[8]*c[2]*c[15]
               + c[8]*c[3]*c[14] + c[12]*c[2]*c[11] - c[12]*c[3]*c[10];
    float i09 = -c[0]*c[9]*c[15] + c[0]*c[11]*c[13] + c[8]*c[1]*c[15]
               - c[8]*c[3]*c[13] - c[12]*c[1]*c[11] + c[12]*c[3]*c[9];
    float i13 =  c[0]*c[9]*c[14] - c[0]*c[10]*c[13] - c[8]*c[1]*c[14]
               + c[8]*c[2]*c[13] + c[12]*c[1]*c[10] - c[12]*c[2]*c[9];
    float i02 =  c[1]*c[6]*c[15] - c[1]*c[7]*c[14] - c[5]*c[2]*c[15]
               + c[5]*c[3]*c[14] + c[13]*c[2]*c[7] - c[13]*c[3]*c[6];
    float i06 = -c[0]*c[6]*c[15] + c[0]*c[7]*c[14] + c[4]*c[2]*c[15]
               - c[4]*c[3]*c[14] - c[12]*c[2]*c[7] + c[12]*c[3]*c[6];
    float i10 =  c[0]*c[5]*c[15] - c[0]*c[7]*c[13] - c[4]*c[1]*c[15]
               + c[4]*c[3]*c[13] + c[12]*c[1]*c[7] - c[12]*c[3]*c[5];
    float i03 = -c[1]*c[6]*c[11] + c[1]*c[7]*c[10] + c[5]*c[2]*c[11]
               - c[5]*c[3]*c[10] - c[9]*c[2]*c[7] + c[9]*c[3]*c[6];
    float i07 =  c[0]*c[6]*c[11] - c[0]*c[7]*c[10] - c[4]*c[2]*c[11]
               + c[4]*c[3]*c[10] + c[8]*c[2]*c[7] - c[8]*c[3]*c[6];
    float i11 = -c[0]*c[5]*c[11] + c[0]*c[7]*c[9] + c[4]*c[1]*c[11]
               - c[4]*c[3]*c[9] - c[8]*c[1]*c[7] + c[8]*c[3]*c[5];
    float det = c[0]*i00 + c[1]*i04 + c[2]*i08 + c[3]*i12;
    float id  = 1.f / det;
    float v00=i00*id, v01=i01*id, v02=i02*id, v03=i03*id;
    float v10=i04*id, v11=i05*id, v12=i06*id, v13=i07*id;
    float v20=i08*id, v21=i09*id, v22=i10*id, v23=i11*id;

    // quaternion -> R, D = (target - predSE3)[:3,:], fold invC in
    const float* q = predT + b*7;
    float qr = q[0], qi = q[1], qj = q[2], qk = q[3];
    float tx = q[4], ty = q[5], tz = q[6];
    float s2 = 2.f / (qr*qr + qi*qi + qj*qj + qk*qk);
    float R00 = 1.f - s2*(qj*qj + qk*qk), R01 = s2*(qi*qj - qk*qr), R02 = s2*(qi*qk + qj*qr);
    float R10 = s2*(qi*qj + qk*qr), R11 = 1.f - s2*(qi*qi + qk*qk), R12 = s2*(qj*qk - qi*qr);
    float R20 = s2*(qi*qk - qj*qr), R21 = s2*(qj*qk + qi*qr), R22 = 1.f - s2*(qi*qi + qj*qj);

    const float* T = target + b*16;
    float D00 = T[0]-R00,  D01 = T[1]-R01,  D02 = T[2]-R02,  D03 = T[3]-tx;
    float D10 = T[4]-R10,  D11 = T[5]-R11,  D12 = T[6]-R12,  D13 = T[7]-ty;
    float D20 = T[8]-R20,  D21 = T[9]-R21,  D22 = T[10]-R22, D23 = T[11]-tz;

    float m00 = D00*v00 + D01*v10 + D02*v20;
    float m01 = D00*v01 + D01*v11 + D02*v21;
    float m02 = D00*v02 + D01*v12 + D02*v22;
    float m10 = D10*v00 + D11*v10 + D12*v20;
    float m11 = D10*v01 + D11*v11 + D12*v21;
    float m12 = D10*v02 + D11*v12 + D12*v22;
    float m20 = D20*v00 + D21*v10 + D22*v20;
    float m21 = D20*v01 + D21*v11 + D22*v21;
    float m22 = D20*v02 + D21*v12 + D22*v22;
    float t0  = D00*v03 + D01*v13 + D02*v23 + D03;
    float t1  = D10*v03 + D11*v13 + D12*v23 + D13;
    float t2  = D20*v03 + D21*v13 + D22*v23 + D23;

    // ---- stream the points
    const int size = sizes[b];
    const float4* p = pts + (size_t)b * N;

    float acc = 0.f;
    for (int n = blk * TPB + tid; n < size; n += PB * TPB) {
        float4 v = p[n];
        float dx = m00*v.x + m01*v.y + m02*v.z + t0;
        float dy = m10*v.x + m11*v.y + m12*v.z + t1;
        float dz = m20*v.x + m21*v.y + m22*v.z + t2;
        acc += sqrtf(dx*dx + dy*dy + dz*dz);
    }

    __shared__ float sm[TPB/64];
    __shared__ bool  isLast;
    for (int off = 32; off > 0; off >>= 1) acc += __shfl_down(acc, off);
    if ((tid & 63) == 0) sm[tid >> 6] = acc;
    __syncthreads();
    if (tid == 0) {
        float s = 0.f;
        #pragma unroll
        for (int w = 0; w < TPB/64; ++w) s += sm[w];
        // device-coherent relaxed store (sc0/sc1) — no L2 writeback
        __hip_atomic_store(&partials[b * PB + blk], s,
                           __ATOMIC_RELAXED, __HIP_MEMORY_SCOPE_AGENT);
        // order our store before the counter bump: wait for our own VMEM acks
        asm volatile("s_waitcnt vmcnt(0)" ::: "memory");
        unsigned old = __hip_atomic_fetch_add(counter, 1u,
                           __ATOMIC_RELAXED, __HIP_MEMORY_SCOPE_AGENT);
        isLast = (old == (unsigned)(PB * B_ - 1));
    }
    __syncthreads();
    if (!isLast) return;

    // ---- last block: final reduction + scalar losses (coherent loads)
    __shared__ float sB[B_];
    {
        int bb = tid >> 3, j = tid & 7;        // 8 threads per batch, 8 slots each
        float s = 0.f;
        const float* pp = partials + bb * PB + j * 8;
        #pragma unroll
        for (int i = 0; i < 8; ++i)
            s += __hip_atomic_load(&pp[i], __ATOMIC_RELAXED, __HIP_MEMORY_SCOPE_AGENT);
        s += __shfl_down(s, 4);
        s += __shfl_down(s, 2);
        s += __shfl_down(s, 1);
        if (j == 0) {
            int sz = sizes[bb];
            sB[bb] = s / (float)(sz > 1 ? sz : 1);
        }
    }
    __syncthreads();

    if (tid < 64) {
        float accE = 0.f, accT = 0.f, accR = 0.f;
        if (tid < B_) {
            accE = sB[tid];
            const float* qq = predT + tid*7;
            float r = qq[0], ii = qq[1], jj = qq[2], kk = qq[3];
            float px = qq[4], py = qq[5], pz = qq[6];
            float ss = 2.f / (r*r + ii*ii + jj*jj + kk*kk);
            float A00 = 1.f - ss*(jj*jj + kk*kk), A01 = ss*(ii*jj - kk*r), A02 = ss*(ii*kk + jj*r);
            float A10 = ss*(ii*jj + kk*r), A11 = 1.f - ss*(ii*ii + kk*kk), A12 = ss*(jj*kk - ii*r);
            float A20 = ss*(ii*kk - jj*r), A21 = ss*(jj*kk + ii*r), A22 = 1.f - ss*(ii*ii + jj*jj);
            const float* TT = target + tid*16;
            float rl = 0.f, m;
            m = A00*TT[0] + A10*TT[4] + A20*TT[8]  - 1.f; rl += m*m;
            m = A00*TT[1] + A10*TT[5] + A20*TT[9];        rl += m*m;
            m = A00*TT[2] + A10*TT[6] + A20*TT[10];       rl += m*m;
            m = A01*TT[0] + A11*TT[4] + A21*TT[8];        rl += m*m;
            m = A01*TT[1] + A11*TT[5] + A21*TT[9]  - 1.f; rl += m*m;
            m = A01*TT[2] + A11*TT[6] + A21*TT[10];       rl += m*m;
            m = A02*TT[0] + A12*TT[4] + A22*TT[8];        rl += m*m;
            m = A02*TT[1] + A12*TT[5] + A22*TT[9];        rl += m*m;
            m = A02*TT[2] + A12*TT[6] + A22*TT[10] - 1.f; rl += m*m;
            accR = sqrtf(rl);
            float dx = px - TT[3], dy = py - TT[7], dz = pz - TT[11];
            accT = sqrtf(dx*dx + dy*dy + dz*dz);
        }
        for (int off = 32; off > 0; off >>= 1) {
            accE += __shfl_down(accE, off);
            accT += __shfl_down(accT, off);
            accR += __shfl_down(accR, off);
        }
        if (tid == 0) {
            float eucl = accE / (float)B_;
            out[0] = eucl + 1.5f * (accT / (float)B_) + 2.0f * (accR / (float)B_);
            out[1] = eucl;
        }
    }
}

extern "C" void kernel_launch(void* const* d_in, const int* in_sizes, int n_in,
                              void* d_out, int out_size, void* d_ws, size_t ws_size,
                              hipStream_t stream) {
    const float* predT  = (const float*)d_in[0];
    const float* ptCld  = (const float*)d_in[1];
    const float* target = (const float*)d_in[2];
    const float* R_rect = (const float*)d_in[3];
    const float* RT     = (const float*)d_in[4];
    const int*   sizes  = (const int*)d_in[5];

    int B = in_sizes[0] / 7;            // == B_ (32)
    int N = in_sizes[1] / (B * 4);

    float*    partials = (float*)d_ws;
    unsigned* counter  = (unsigned*)(partials + B * PB);
    float*    out      = (float*)d_out;

    hipMemsetAsync(counter, 0, sizeof(unsigned), stream);
    fused_kernel<<<dim3(PB, B), TPB, 0, stream>>>(
        predT, (const float4*)ptCld, target, R_rect, RT, sizes,
        partials, counter, out, N);
}

// Round 8
// 19.379 us; speedup vs baseline: 3.5185x; 2.0011x over previous
//
#include <hip/hip_runtime.h>
#include <math.h>

#define PB  64    // blocks per batch
#define TPB 256
#define B_  32    // batch count (fixed by setup_inputs)

// ws layout: float partials[B_*PB] — every slot unconditionally written by
// dist_kernel each call (no carried state, no memset needed).
// Cross-block visibility comes from the kernel boundary (AQL barrier
// release/acquire) — proven exact in round 1, and cheap (~2-4us), unlike
// memset blit nodes (~40us of cache maintenance) or __threadfence
// (buffer_wbl2, ~55us aggregate) measured in rounds 2-4.

__global__ __launch_bounds__(TPB) void dist_kernel(
    const float* __restrict__ predT,
    const float4* __restrict__ pts,
    const float* __restrict__ target,
    const float* __restrict__ R_rect,
    const float* __restrict__ RT,
    const int* __restrict__ sizes,
    float* __restrict__ partials,
    int N)
{
    const int b   = blockIdx.y;
    const int blk = blockIdx.x;
    const int tid = threadIdx.x;

    // ---- per-thread redundant prep: branch-free, static-index only (registers)
    float c[16];
    #pragma unroll
    for (int i = 0; i < 4; ++i)
        #pragma unroll
        for (int j = 0; j < 4; ++j)
            c[i*4+j] = R_rect[i*4+0]*RT[0*4+j] + R_rect[i*4+1]*RT[1*4+j]
                     + R_rect[i*4+2]*RT[2*4+j] + R_rect[i*4+3]*RT[3*4+j];

    // adjugate inverse rows 0..2 (inv = adj/det), all named scalars
    float i00 =  c[5]*c[10]*c[15] - c[5]*c[11]*c[14] - c[9]*c[6]*c[15]
               + c[9]*c[7]*c[14] + c[13]*c[6]*c[11] - c[13]*c[7]*c[10];
    float i04 = -c[4]*c[10]*c[15] + c[4]*c[11]*c[14] + c[8]*c[6]*c[15]
               - c[8]*c[7]*c[14] - c[12]*c[6]*c[11] + c[12]*c[7]*c[10];
    float i08 =  c[4]*c[9]*c[15] - c[4]*c[11]*c[13] - c[8]*c[5]*c[15]
               + c[8]*c[7]*c[13] + c[12]*c[5]*c[11] - c[12]*c[7]*c[9];
    float i12 = -c[4]*c[9]*c[14] + c[4]*c[10]*c[13] + c[8]*c[5]*c[14]
               - c[8]*c[6]*c[13] - c[12]*c[5]*c[10] + c[12]*c[6]*c[9];
    float i01 = -c[1]*c[10]*c[15] + c[1]*c[11]*c[14] + c[9]*c[2]*c[15]
               - c[9]*c[3]*c[14] - c[13]*c[2]*c[11] + c[13]*c[3]*c[10];
    float i05 =  c[0]*c[10]*c[15] - c[0]*c[11]*c[14] - c[8]*c[2]*c[15]
               + c[8]*c[3]*c[14] + c[12]*c[2]*c[11] - c[12]*c[3]*c[10];
    float i09 = -c[0]*c[9]*c[15] + c[0]*c[11]*c[13] + c[8]*c[1]*c[15]
               - c[8]*c[3]*c[13] - c[12]*c[1]*c[11] + c[12]*c[3]*c[9];
    float i02 =  c[1]*c[6]*c[15] - c[1]*c[7]*c[14] - c[5]*c[2]*c[15]
               + c[5]*c[3]*c[14] + c[13]*c[2]*c[7] - c[13]*c[3]*c[6];
    float i06 = -c[0]*c[6]*c[15] + c[0]*c[7]*c[14] + c[4]*c[2]*c[15]
               - c[4]*c[3]*c[14] - c[12]*c[2]*c[7] + c[12]*c[3]*c[6];
    float i10 =  c[0]*c[5]*c[15] - c[0]*c[7]*c[13] - c[4]*c[1]*c[15]
               + c[4]*c[3]*c[13] + c[12]*c[1]*c[7] - c[12]*c[3]*c[5];
    float i03 = -c[1]*c[6]*c[11] + c[1]*c[7]*c[10] + c[5]*c[2]*c[11]
               - c[5]*c[3]*c[10] - c[9]*c[2]*c[7] + c[9]*c[3]*c[6];
    float i07 =  c[0]*c[6]*c[11] - c[0]*c[7]*c[10] - c[4]*c[2]*c[11]
               + c[4]*c[3]*c[10] + c[8]*c[2]*c[7] - c[8]*c[3]*c[6];
    float i11 = -c[0]*c[5]*c[11] + c[0]*c[7]*c[9] + c[4]*c[1]*c[11]
               - c[4]*c[3]*c[9] - c[8]*c[1]*c[7] + c[8]*c[3]*c[5];
    float det = c[0]*i00 + c[1]*i04 + c[2]*i08 + c[3]*i12;
    float id  = 1.f / det;
    float v00=i00*id, v01=i01*id, v02=i02*id, v03=i03*id;
    float v10=i04*id, v11=i05*id, v12=i06*id, v13=i07*id;
    float v20=i08*id, v21=i09*id, v22=i10*id, v23=i11*id;

    // quaternion -> R, D = (target - predSE3)[:3,:], fold invC in
    const float* q = predT + b*7;
    float qr = q[0], qi = q[1], qj = q[2], qk = q[3];
    float tx = q[4], ty = q[5], tz = q[6];
    float s2 = 2.f / (qr*qr + qi*qi + qj*qj + qk*qk);
    float R00 = 1.f - s2*(qj*qj + qk*qk), R01 = s2*(qi*qj - qk*qr), R02 = s2*(qi*qk + qj*qr);
    float R10 = s2*(qi*qj + qk*qr), R11 = 1.f - s2*(qi*qi + qk*qk), R12 = s2*(qj*qk - qi*qr);
    float R20 = s2*(qi*qk - qj*qr), R21 = s2*(qj*qk + qi*qr), R22 = 1.f - s2*(qi*qi + qj*qj);

    const float* T = target + b*16;
    float D00 = T[0]-R00,  D01 = T[1]-R01,  D02 = T[2]-R02,  D03 = T[3]-tx;
    float D10 = T[4]-R10,  D11 = T[5]-R11,  D12 = T[6]-R12,  D13 = T[7]-ty;
    float D20 = T[8]-R20,  D21 = T[9]-R21,  D22 = T[10]-R22, D23 = T[11]-tz;

    float m00 = D00*v00 + D01*v10 + D02*v20;
    float m01 = D00*v01 + D01*v11 + D02*v21;
    float m02 = D00*v02 + D01*v12 + D02*v22;
    float m10 = D10*v00 + D11*v10 + D12*v20;
    float m11 = D10*v01 + D11*v11 + D12*v21;
    float m12 = D10*v02 + D11*v12 + D12*v22;
    float m20 = D20*v00 + D21*v10 + D22*v20;
    float m21 = D20*v01 + D21*v11 + D22*v21;
    float m22 = D20*v02 + D21*v12 + D22*v22;
    float t0  = D00*v03 + D01*v13 + D02*v23 + D03;
    float t1  = D10*v03 + D11*v13 + D12*v23 + D13;
    float t2  = D20*v03 + D21*v13 + D22*v23 + D23;

    // ---- stream the points
    const int size = sizes[b];
    const float4* p = pts + (size_t)b * N;

    float acc = 0.f;
    for (int n = blk * TPB + tid; n < size; n += PB * TPB) {
        float4 v = p[n];
        float dx = m00*v.x + m01*v.y + m02*v.z + t0;
        float dy = m10*v.x + m11*v.y + m12*v.z + t1;
        float dz = m20*v.x + m21*v.y + m22*v.z + t2;
        acc += sqrtf(dx*dx + dy*dy + dz*dz);
    }

    __shared__ float sm[TPB/64];
    for (int off = 32; off > 0; off >>= 1) acc += __shfl_down(acc, off);
    if ((tid & 63) == 0) sm[tid >> 6] = acc;
    __syncthreads();
    if (tid == 0) {
        float s = 0.f;
        #pragma unroll
        for (int w = 0; w < TPB/64; ++w) s += sm[w];
        partials[b * PB + blk] = s;   // fixed slot -> deterministic
    }
}

__global__ __launch_bounds__(TPB) void final_kernel(
    const float* __restrict__ predT,
    const float* __restrict__ target,
    const int* __restrict__ sizes,
    const float* __restrict__ partials,
    float* __restrict__ out)
{
    const int tid = threadIdx.x;
    __shared__ float sB[B_];
    {
        int bb = tid >> 3, j = tid & 7;        // 8 threads per batch, 8 slots each
        float s = 0.f;
        const float* pp = partials + bb * PB + j * 8;
        #pragma unroll
        for (int i = 0; i < 8; ++i) s += pp[i];
        s += __shfl_down(s, 4);
        s += __shfl_down(s, 2);
        s += __shfl_down(s, 1);
        if (j == 0) {
            int sz = sizes[bb];
            sB[bb] = s / (float)(sz > 1 ? sz : 1);
        }
    }
    __syncthreads();

    if (tid < 64) {
        float accE = 0.f, accT = 0.f, accR = 0.f;
        if (tid < B_) {
            accE = sB[tid];
            const float* qq = predT + tid*7;
            float r = qq[0], ii = qq[1], jj = qq[2], kk = qq[3];
            float px = qq[4], py = qq[5], pz = qq[6];
            float ss = 2.f / (r*r + ii*ii + jj*jj + kk*kk);
            float A00 = 1.f - ss*(jj*jj + kk*kk), A01 = ss*(ii*jj - kk*r), A02 = ss*(ii*kk + jj*r);
            float A10 = ss*(ii*jj + kk*r), A11 = 1.f - ss*(ii*ii + kk*kk), A12 = ss*(jj*kk - ii*r);
            float A20 = ss*(ii*kk - jj*r), A21 = ss*(jj*kk + ii*r), A22 = 1.f - ss*(ii*ii + jj*jj);
            const float* TT = target + tid*16;
            float rl = 0.f, m;
            m = A00*TT[0] + A10*TT[4] + A20*TT[8]  - 1.f; rl += m*m;
            m = A00*TT[1] + A10*TT[5] + A20*TT[9];        rl += m*m;
            m = A00*TT[2] + A10*TT[6] + A20*TT[10];       rl += m*m;
            m = A01*TT[0] + A11*TT[4] + A21*TT[8];        rl += m*m;
            m = A01*TT[1] + A11*TT[5] + A21*TT[9]  - 1.f; rl += m*m;
            m = A01*TT[2] + A11*TT[6] + A21*TT[10];       rl += m*m;
            m = A02*TT[0] + A12*TT[4] + A22*TT[8];        rl += m*m;
            m = A02*TT[1] + A12*TT[5] + A22*TT[9];        rl += m*m;
            m = A02*TT[2] + A12*TT[6] + A22*TT[10] - 1.f; rl += m*m;
            accR = sqrtf(rl);
            float dx = px - TT[3], dy = py - TT[7], dz = pz - TT[11];
            accT = sqrtf(dx*dx + dy*dy + dz*dz);
        }
        for (int off = 32; off > 0; off >>= 1) {
            accE += __shfl_down(accE, off);
            accT += __shfl_down(accT, off);
            accR += __shfl_down(accR, off);
        }
        if (tid == 0) {
            float eucl = accE / (float)B_;
            out[0] = eucl + 1.5f * (accT / (float)B_) + 2.0f * (accR / (float)B_);
            out[1] = eucl;
        }
    }
}

extern "C" void kernel_launch(void* const* d_in, const int* in_sizes, int n_in,
                              void* d_out, int out_size, void* d_ws, size_t ws_size,
                              hipStream_t stream) {
    const float* predT  = (const float*)d_in[0];
    const float* ptCld  = (const float*)d_in[1];
    const float* target = (const float*)d_in[2];
    const float* R_rect = (const float*)d_in[3];
    const float* RT     = (const float*)d_in[4];
    const int*   sizes  = (const int*)d_in[5];

    int B = in_sizes[0] / 7;            // == B_ (32)
    int N = in_sizes[1] / (B * 4);

    float* partials = (float*)d_ws;
    float* out      = (float*)d_out;

    dist_kernel<<<dim3(PB, B), TPB, 0, stream>>>(
        predT, (const float4*)ptCld, target, R_rect, RT, sizes, partials, N);
    final_kernel<<<1, TPB, 0, stream>>>(predT, target, sizes, partials, out);
}